// Round 13
// baseline (689.423 us; speedup 1.0000x reference)
//
#include <hip/hip_runtime.h>
#include <cstdint>
#include <cstddef>

#define NN 200000
#define NE 600000
#define NG 8192
#define C0 32
#define C1 128
#define C2 256
#define MLPH 256
#define NCLS 10
#define NB (3 * NN)
#define SCAN_BPB 1024
#define SCAN_NBLK ((NB + SCAN_BPB - 1) / SCAN_BPB)
#define NREP 8   // stats atomic replication
#define MGB 32   // graphs per k_mlp block

typedef __attribute__((ext_vector_type(8))) short short8b;  // 8 bf16 = 4 VGPR
typedef __attribute__((ext_vector_type(4))) float f32x4;

__device__ __forceinline__ void atomAddF(float* p, float v) { unsafeAtomicAdd(p, v); }

__device__ __forceinline__ float b2f(unsigned short u) {
  union { unsigned u; float f; } v; v.u = ((unsigned)u) << 16; return v.f;
}
__device__ __forceinline__ unsigned short f2b(float f) {  // RNE
  union { float f; unsigned u; } v; v.f = f;
  return (unsigned short)((v.u + 0x7FFF + ((v.u >> 16) & 1)) >> 16);
}

// ---------------- small utility kernels ----------------
__global__ __launch_bounds__(256) void k_fill(float* __restrict__ p, int n, float v) {
  int i = blockIdx.x * 256 + threadIdx.x;
  if (i < n) p[i] = v;
}

__global__ __launch_bounds__(256) void k_counts(const int* __restrict__ batch, float* __restrict__ counts) {
  int n = blockIdx.x * 256 + threadIdx.x;
  if (n < NN) atomAddF(&counts[batch[n]], 1.f);
}

// ---------------- CSR build: histogram (= degree), scan, place ----------------
__global__ __launch_bounds__(256) void k_hist(const int* __restrict__ dst, const int* __restrict__ et,
                                              int* __restrict__ cnt) {
  int e = blockIdx.x * 256 + threadIdx.x;
  if (e < NE) atomicAdd(&cnt[et[e] * NN + dst[e]], 1);
}

__global__ __launch_bounds__(256) void k_dinvI(const int* __restrict__ cnt, float* __restrict__ dinv) {
  int i = blockIdx.x * 256 + threadIdx.x;
  if (i < NB) { int c = cnt[i]; dinv[i] = (c > 0) ? 1.f / sqrtf((float)c) : 0.f; }
}

__global__ __launch_bounds__(256) void k_scan1(const int* __restrict__ cnt, int* __restrict__ starts,
                                               int* __restrict__ bsum) {
  __shared__ int sh[256];
  const int b0 = blockIdx.x * SCAN_BPB + threadIdx.x * 4;
  int v[4]; int tot = 0;
#pragma unroll
  for (int j = 0; j < 4; j++) {
    int b = b0 + j;
    v[j] = tot;
    tot += (b < NB) ? cnt[b] : 0;
  }
  sh[threadIdx.x] = tot;
  __syncthreads();
  for (int ofs = 1; ofs < 256; ofs <<= 1) {
    int add = (threadIdx.x >= ofs) ? sh[threadIdx.x - ofs] : 0;
    __syncthreads();
    sh[threadIdx.x] += add;
    __syncthreads();
  }
  const int excl = (threadIdx.x == 0) ? 0 : sh[threadIdx.x - 1];
#pragma unroll
  for (int j = 0; j < 4; j++) {
    int b = b0 + j;
    if (b < NB) starts[b] = excl + v[j];
  }
  if (threadIdx.x == 255) bsum[blockIdx.x] = sh[255];
}

__global__ void k_scan2(int* __restrict__ bsum) {
  if (threadIdx.x == 0) {
    int acc = 0;
    for (int i = 0; i < SCAN_NBLK; i++) { int t = bsum[i]; bsum[i] = acc; acc += t; }
  }
}

__global__ __launch_bounds__(256) void k_scan3(int* __restrict__ starts, const int* __restrict__ bsum) {
  int b = blockIdx.x * 256 + threadIdx.x;
  if (b < NB) starts[b] += bsum[b / SCAN_BPB];
}

// After k_place, starts[b] == end(b); list for bin b = [b ? starts[b-1] : 0, starts[b])
__global__ __launch_bounds__(256) void k_place(const int* __restrict__ src, const int* __restrict__ dst,
                                               const int* __restrict__ et, int* __restrict__ starts,
                                               int* __restrict__ esrc) {
  int e = blockIdx.x * 256 + threadIdx.x;
  if (e >= NE) return;
  int b = et[e] * NN + dst[e];
  int pos = atomicAdd(&starts[b], 1);
  esrc[pos] = src[e];
}

// ---------------- weight prep: fragment-ordered bf16 ----------------
// [m:4][p:COUT/64][kk:CIN/32][ct:4][l:64][j:8]; ki = kk*32+(l>>4)*4+(j&3)+16*(j>>2), c = p*64+ct*16+(l&15)
__global__ __launch_bounds__(256) void k_prepw(const float* __restrict__ Wid, const float* __restrict__ Wc,
                                               unsigned short* __restrict__ Wtf, int CIN_, int COUT_) {
  int i = blockIdx.x * 256 + threadIdx.x;
  if (i >= 4 * CIN_ * COUT_) return;
  int j = i & 7, lq = (i >> 3) & 63, ct = (i >> 9) & 3;
  int rest = i >> 11;
  int KK = CIN_ / 32, NP = COUT_ / 64;
  int kk = rest % KK; rest /= KK;
  int p = rest % NP; int m = rest / NP;
  int ki = kk * 32 + (lq >> 4) * 4 + (j & 3) + 16 * (j >> 2);
  int c = p * 64 + ct * 16 + (lq & 15);
  float wv = (m == 0) ? Wid[(size_t)ki * COUT_ + c] : Wc[(size_t)((m - 1) * CIN_ + ki) * COUT_ + c];
  Wtf[i] = f2b(wv);
}

// ---------------- gather-reduce aggregation (CSR) ----------------
template <int CIN, typename TIN>
__global__ __launch_bounds__(256) void k_agg(const int* __restrict__ starts, const int* __restrict__ esrc,
                                             const float* __restrict__ dinv, const TIN* __restrict__ h,
                                             unsigned short* __restrict__ aggXb, int lo, int nloc) {
  constexpr int TPB = (CIN == 32) ? 8 : 16;
  constexpr int V = CIN / TPB;  // 4 (f32) or 8 (bf16)
  const int idx = blockIdx.x * 256 + threadIdx.x;
  const int bl = idx / TPB;
  const int lane = idx % TPB;
  if (bl >= 3 * nloc) return;
  const int t = bl / nloc;
  const int bin = t * NN + lo + (bl - t * nloc);
  const int s = (bin == 0) ? 0 : starts[bin - 1];
  const int e2 = starts[bin];
  float acc[V];
#pragma unroll
  for (int j = 0; j < V; j++) acc[j] = 0.f;
  for (int i = s; i < e2; i++) {
    const int sn = esrc[i];
    const float dv = dinv[(size_t)t * NN + sn];
    if (dv == 0.f) continue;
    const TIN* hp = h + (size_t)sn * CIN + lane * V;
    if constexpr (sizeof(TIN) == 2) {
      ushort4 u0 = *(const ushort4*)hp;
      ushort4 u1 = *(const ushort4*)((const unsigned short*)hp + 4);
      acc[0] = fmaf(b2f(u0.x), dv, acc[0]); acc[1] = fmaf(b2f(u0.y), dv, acc[1]);
      acc[2] = fmaf(b2f(u0.z), dv, acc[2]); acc[3] = fmaf(b2f(u0.w), dv, acc[3]);
      if constexpr (V == 8) {
        acc[4] = fmaf(b2f(u1.x), dv, acc[4]); acc[5] = fmaf(b2f(u1.y), dv, acc[5]);
        acc[6] = fmaf(b2f(u1.z), dv, acc[6]); acc[7] = fmaf(b2f(u1.w), dv, acc[7]);
      }
    } else {
      float4 v0 = *(const float4*)hp;
      acc[0] = fmaf(v0.x, dv, acc[0]); acc[1] = fmaf(v0.y, dv, acc[1]);
      acc[2] = fmaf(v0.z, dv, acc[2]); acc[3] = fmaf(v0.w, dv, acc[3]);
    }
  }
  const float dvd = dinv[bin];
  unsigned short* op = aggXb + (size_t)bl * CIN + lane * V;
  ushort4 o0;
  o0.x = f2b(acc[0] * dvd); o0.y = f2b(acc[1] * dvd);
  o0.z = f2b(acc[2] * dvd); o0.w = f2b(acc[3] * dvd);
  *(ushort4*)op = o0;
  if constexpr (V == 8) {
    ushort4 o1;
    o1.x = f2b(acc[4] * dvd); o1.y = f2b(acc[5] * dvd);
    o1.z = f2b(acc[6] * dvd); o1.w = f2b(acc[7] * dvd);
    *(ushort4*)(op + 4) = o1;
  }
}

// ---------------- fused finish: 2 adjacent 64-row tiles per block ----------------
// Round-12 pipeline (LDS weight dbuf, split stage, A-prefetch) with T0/T1 interleave:
// each m-phase does 32 MFMA/wave; T1 loads cover T0 compute and vice versa.
#define SLOAD(mm)                                                                        \
  {                                                                                      \
    const short8b* g_ = (const short8b*)Wtf + (size_t)((mm) * NP + p) * PMF;             \
    _Pragma("unroll") for (int ii_ = 0; ii_ < KK; ii_++) wreg[ii_] = g_[ii_ * 256 + tid];\
  }

#define SWRITE(mm)                                                                       \
  {                                                                                      \
    short8b* d_ = wlds + ((mm) & 1) * PMF;                                               \
    _Pragma("unroll") for (int ii_ = 0; ii_ < KK; ii_++) d_[ii_ * 256 + tid] = wreg[ii_];\
  }

#define LOADA_T(A0, A1, mm, TOFF)                                                        \
  {                                                                                      \
    const int rr_ = ln0 + (TOFF) + rA;                                                   \
    if constexpr ((mm) > 0) {                                                            \
      const unsigned short* ar_ = aggXb + ((size_t)((mm)-1) * nloc + rr_) * CIN;         \
      _Pragma("unroll") for (int kk_ = 0; kk_ < KK; kk_++) {                             \
        A0[kk_] = *(const ushort4*)(ar_ + kk_ * 32 + lq * 4);                            \
        A1[kk_] = *(const ushort4*)(ar_ + kk_ * 32 + 16 + lq * 4);                       \
      }                                                                                  \
    } else if constexpr (INBF16) {                                                       \
      const unsigned short* xr_ = (const unsigned short*)Xv + (size_t)(lo + rr_) * CIN;  \
      _Pragma("unroll") for (int kk_ = 0; kk_ < KK; kk_++) {                             \
        A0[kk_] = *(const ushort4*)(xr_ + kk_ * 32 + lq * 4);                            \
        A1[kk_] = *(const ushort4*)(xr_ + kk_ * 32 + 16 + lq * 4);                       \
      }                                                                                  \
    } else {                                                                             \
      const float* xr_ = (const float*)Xv + (size_t)(lo + rr_) * CIN;                    \
      _Pragma("unroll") for (int kk_ = 0; kk_ < KK; kk_++) {                             \
        float4 v0_ = *(const float4*)(xr_ + kk_ * 32 + lq * 4);                          \
        float4 v1_ = *(const float4*)(xr_ + kk_ * 32 + 16 + lq * 4);                     \
        A0[kk_] = make_ushort4(f2b(v0_.x), f2b(v0_.y), f2b(v0_.z), f2b(v0_.w));          \
        A1[kk_] = make_ushort4(f2b(v1_.x), f2b(v1_.y), f2b(v1_.z), f2b(v1_.w));          \
      }                                                                                  \
    }                                                                                    \
  }

#define COMPM_R(A0, A1, mm, RUN)                                                         \
  {                                                                                      \
    f32x4 acc_[4];                                                                       \
    _Pragma("unroll") for (int c_ = 0; c_ < 4; c_++) acc_[c_] = (f32x4){0.f, 0.f, 0.f, 0.f}; \
    const short8b* wb_ = wlds + ((mm) & 1) * PMF;                                        \
    _Pragma("unroll") for (int kk_ = 0; kk_ < KK; kk_++) {                               \
      union { ushort4 u4[2]; short8b v; } fa_;                                           \
      fa_.u4[0] = A0[kk_]; fa_.u4[1] = A1[kk_];                                          \
      _Pragma("unroll") for (int c_ = 0; c_ < 4; c_++)                                   \
          acc_[c_] = __builtin_amdgcn_mfma_f32_16x16x32_bf16(                            \
              fa_.v, wb_[kk_ * 256 + c_ * 64 + l], acc_[c_], 0, 0, 0);                   \
    }                                                                                    \
    const float* bp_ = ((mm) == 0) ? bid : bc + (size_t)((mm)-1) * COUT;                 \
    _Pragma("unroll") for (int c_ = 0; c_ < 4; c_++) {                                   \
      float bb_ = bp_[c0 + c_ * 16 + lr];                                                \
      _Pragma("unroll") for (int j_ = 0; j_ < 4; j_++)                                   \
          RUN[c_][j_] += fmaxf(acc_[c_][j_] + bb_, 0.f);                                 \
    }                                                                                    \
  }

template <int CIN, int COUT, bool INBF16, bool WRITEOUT, bool DOPOOL>
__global__ __launch_bounds__(256, 3) void k_fin(
    const void* __restrict__ Xv, const unsigned short* __restrict__ aggXb,
    int lo, int nloc, int nt, const unsigned short* __restrict__ Wtf,
    const float* __restrict__ bid, const float* __restrict__ bc,
    unsigned short* __restrict__ outb, float* __restrict__ stats,
    float* __restrict__ pooled, const int* __restrict__ batch) {
  constexpr int NP = COUT / 64;
  constexpr int KK = CIN / 32;
  constexpr int PMF = KK * 256;                       // frags per (m,panel) slice
  constexpr int EPI = 64 * 65 * 4 + 2 * 4 * 64 * 4 + 128 * 4;  // tile + sred + sbatch[128]
  constexpr int SMEM_BYTES = (2 * PMF * 16 > EPI) ? 2 * PMF * 16 : EPI;
  __shared__ __align__(16) char smem[SMEM_BYTES];
  short8b* wlds = (short8b*)smem;                     // [2][PMF]
  float (*tile)[65] = (float(*)[65])smem;             // epilogue aliases
  float* sred = (float*)(smem + 64 * 65 * 4);         // [2][4][64]
  int* sbatch = (int*)(smem + 64 * 65 * 4 + 2 * 4 * 64 * 4);  // [128]

  // ---- XCD swizzle decode over tile-pairs: i = xr8 + 8*(tpi*NP + p) ----
  const int i = blockIdx.x;
  const int xr8 = i & 7;
  const int xq = i >> 3;
  const int p = xq % NP;
  const int tpi = xq / NP;
  const int tp = tpi * 8 + xr8;
  const int nt2 = (nt + 1) >> 1;
  if (tp >= nt2) return;
  const int t0 = tp * 2;
  const bool have2 = (t0 + 1) < nt;
  const int ln0 = t0 * 64;            // T0 rows [ln0, ln0+64); T1 rows [ln0+64, ln0+128)
  const int n0 = lo + ln0;
  const int c0 = p * 64;
  const int tid = threadIdx.x, w = tid >> 6, l = tid & 63, lr = l & 15, lq = l >> 4;
  const int rA = w * 16 + lr;

  f32x4 run0[4], run1[4];
#pragma unroll
  for (int ct = 0; ct < 4; ct++) { run0[ct] = (f32x4){0.f, 0.f, 0.f, 0.f}; run1[ct] = run0[ct]; }

  short8b wreg[KK];
  ushort4 a00[KK], a01[KK], a10[KK], a11[KK];

  // ---- prologue ----
  SLOAD(0)
  LOADA_T(a00, a01, 0, 0)
  SWRITE(0)
  __syncthreads();
  // ---- m=0 ----
  SLOAD(1)
  if (have2) LOADA_T(a10, a11, 0, 64)
  COMPM_R(a00, a01, 0, run0)
  LOADA_T(a00, a01, 1, 0)
  if (have2) COMPM_R(a10, a11, 0, run1)
  SWRITE(1)
  __syncthreads();
  // ---- m=1 ----
  SLOAD(2)
  if (have2) LOADA_T(a10, a11, 1, 64)
  COMPM_R(a00, a01, 1, run0)
  LOADA_T(a00, a01, 2, 0)
  if (have2) COMPM_R(a10, a11, 1, run1)
  SWRITE(2)
  __syncthreads();
  // ---- m=2 ----
  SLOAD(3)
  if (have2) LOADA_T(a10, a11, 2, 64)
  COMPM_R(a00, a01, 2, run0)
  LOADA_T(a00, a01, 3, 0)
  if (have2) COMPM_R(a10, a11, 2, run1)
  SWRITE(3)
  __syncthreads();
  // ---- m=3 ----
  if (have2) LOADA_T(a10, a11, 3, 64)
  COMPM_R(a00, a01, 3, run0)
  if (have2) COMPM_R(a10, a11, 3, run1)
  __syncthreads();  // all waves done with wlds; epilogue may alias

  if (tid < 128 && (have2 || tid < 64)) sbatch[tid] = DOPOOL ? batch[n0 + tid] : 0;

  auto epi = [&](f32x4 (&RUN)[4], int TOFF) {
#pragma unroll
    for (int ct = 0; ct < 4; ct++)
#pragma unroll
      for (int j = 0; j < 4; j++) tile[w * 16 + lq * 4 + j][ct * 16 + lr] = RUN[ct][j];
    __syncthreads();
    if (WRITEOUT) {
      const int r = tid >> 2, cg = (tid & 3) * 16;
      ushort4 o[4];
#pragma unroll
      for (int g4 = 0; g4 < 4; g4++) {
        o[g4].x = f2b(tile[r][cg + g4 * 4 + 0]);
        o[g4].y = f2b(tile[r][cg + g4 * 4 + 1]);
        o[g4].z = f2b(tile[r][cg + g4 * 4 + 2]);
        o[g4].w = f2b(tile[r][cg + g4 * 4 + 3]);
      }
      ushort4* dst4 = (ushort4*)(outb + (size_t)(n0 + TOFF + r) * COUT + c0 + cg);
#pragma unroll
      for (int g4 = 0; g4 < 4; g4++) dst4[g4] = o[g4];
    }
    {
      const int col = tid & 63, rg = tid >> 6, r0 = rg * 16;
      float s = 0.f, ss = 0.f, gs = 0.f;
      int curg = DOPOOL ? sbatch[TOFF + r0] : 0;
#pragma unroll
      for (int r = 0; r < 16; r++) {
        float v = tile[r0 + r][col];
        s += v; ss += v * v;
        if (DOPOOL) {
          int g = sbatch[TOFF + r0 + r];
          if (g != curg) { atomAddF(&pooled[(size_t)curg * C2 + c0 + col], gs); gs = 0.f; curg = g; }
          gs += v;
        }
      }
      if (DOPOOL) atomAddF(&pooled[(size_t)curg * C2 + c0 + col], gs);
      sred[0 * 4 * 64 + rg * 64 + col] = s;
      sred[1 * 4 * 64 + rg * 64 + col] = ss;
    }
    __syncthreads();
    if (tid < 64) {
      float s4 = sred[0 + tid] + sred[64 + tid] + sred[128 + tid] + sred[192 + tid];
      float ss4 = sred[256 + tid] + sred[320 + tid] + sred[384 + tid] + sred[448 + tid];
      float* st = stats + (size_t)(t0 & (NREP - 1)) * 2 * COUT;
      atomAddF(&st[c0 + tid], s4);
      atomAddF(&st[COUT + c0 + tid], ss4);
    }
  };
  epi(run0, 0);
  if (have2) {
    __syncthreads();
    epi(run1, 64);
  }
}

// ---------------- BN finalize (sums NREP replicas) -> per-channel scale/shift ----------------
__global__ __launch_bounds__(256) void k_bnfin(const float* __restrict__ stats, const float* __restrict__ gamma,
                                               const float* __restrict__ beta, float* __restrict__ sc,
                                               float* __restrict__ sh, int COUT) {
  int c = threadIdx.x;
  if (c < COUT) {
    float su = 0.f, ssu = 0.f;
    for (int r = 0; r < NREP; r++) {
      su += stats[(size_t)r * 2 * COUT + c];
      ssu += stats[(size_t)r * 2 * COUT + COUT + c];
    }
    const float invN = 1.f / (float)NN;
    float m = su * invN;
    float v = ssu * invN - m * m;
    float s = gamma[c] / sqrtf(v + 1e-5f);
    sc[c] = s;
    sh[c] = fmaf(-m, s, beta[c]);
  }
}

// ---------------- fold BN1 into out1 (bf16, in place) ----------------
__global__ __launch_bounds__(256) void k_bnfold(unsigned short* __restrict__ o, const float* __restrict__ sc,
                                                const float* __restrict__ sh) {
  size_t i8 = ((size_t)blockIdx.x * 256 + threadIdx.x) * 8;
  if (i8 >= (size_t)NN * C1) return;
  const int c = (int)(i8 & (C1 - 1));
  ushort4 a = *(ushort4*)(o + i8);
  ushort4 b = *(ushort4*)(o + i8 + 4);
  a.x = f2b(fmaf(b2f(a.x), sc[c + 0], sh[c + 0]));
  a.y = f2b(fmaf(b2f(a.y), sc[c + 1], sh[c + 1]));
  a.z = f2b(fmaf(b2f(a.z), sc[c + 2], sh[c + 2]));
  a.w = f2b(fmaf(b2f(a.w), sc[c + 3], sh[c + 3]));
  b.x = f2b(fmaf(b2f(b.x), sc[c + 4], sh[c + 4]));
  b.y = f2b(fmaf(b2f(b.y), sc[c + 5], sh[c + 5]));
  b.z = f2b(fmaf(b2f(b.z), sc[c + 6], sh[c + 6]));
  b.w = f2b(fmaf(b2f(b.w), sc[c + 7], sh[c + 7]));
  *(ushort4*)(o + i8) = a;
  *(ushort4*)(o + i8 + 4) = b;
}

// ---------------- MLP head, graph-tiled: 32 graphs/block, Wf1 read once per block ----------------
__global__ __launch_bounds__(256) void k_mlp(const float* __restrict__ pooled, const float* __restrict__ counts,
                                             const float* __restrict__ sc2, const float* __restrict__ sh2,
                                             const float* __restrict__ Wf1, const float* __restrict__ bf1,
                                             const float* __restrict__ Wf2, const float* __restrict__ bf2,
                                             float* __restrict__ out) {
  __shared__ float featT[257 * 36];  // [i][g], pad 36 (16B-aligned rows); aliased as hidT[256][36]
  __shared__ float cnts[MGB];
  const int g0 = blockIdx.x * MGB;
  const int t = threadIdx.x;
  if (t < MGB) cnts[t] = counts[g0 + t];
  __syncthreads();
  {
    const float sc = sc2[t], sh = sh2[t];
    for (int g = 0; g < MGB; g++)
      featT[t * 36 + g] = fmaf(sc, pooled[(size_t)(g0 + g) * C2 + t], sh * cnts[g]);
  }
  if (t < MGB) featT[256 * 36 + t] = cnts[t] * 0.025f;  // count/40 feature
  __syncthreads();
  float acc[MGB];
  const float b1 = bf1[t];
#pragma unroll
  for (int g = 0; g < MGB; g++) acc[g] = b1;
  for (int i = 0; i < 257; i++) {
    const float wv = Wf1[(size_t)i * MLPH + t];
    const float* fr = &featT[i * 36];
#pragma unroll
    for (int g4 = 0; g4 < MGB / 4; g4++) {
      float4 fg = *(const float4*)(fr + g4 * 4);
      acc[g4 * 4 + 0] = fmaf(fg.x, wv, acc[g4 * 4 + 0]);
      acc[g4 * 4 + 1] = fmaf(fg.y, wv, acc[g4 * 4 + 1]);
      acc[g4 * 4 + 2] = fmaf(fg.z, wv, acc[g4 * 4 + 2]);
      acc[g4 * 4 + 3] = fmaf(fg.w, wv, acc[g4 * 4 + 3]);
    }
  }
  __syncthreads();  // featT fully consumed
  float* hidT = featT;  // alias: [j][g] with stride 36
#pragma unroll
  for (int g = 0; g < MGB; g++) hidT[t * 36 + g] = fmaxf(acc[g], 0.f);
  __syncthreads();
  for (int task = t; task < MGB * NCLS; task += 256) {
    const int g = task / NCLS, c = task % NCLS;
    float o = bf2[c];
    for (int j = 0; j < MLPH; j++) o = fmaf(hidT[j * 36 + g], Wf2[(size_t)j * NCLS + c], o);
    out[(size_t)(g0 + g) * NCLS + c] = o;
  }
}

extern "C" void kernel_launch(void* const* d_in, const int* in_sizes, int n_in,
                              void* d_out, int out_size, void* d_ws, size_t ws_size,
                              hipStream_t stream) {
  const float* x = (const float*)d_in[0];
  const int* ei = (const int*)d_in[1];
  const int* et = (const int*)d_in[2];
  const int* batch = (const int*)d_in[3];
  const float* Wc0 = (const float*)d_in[4];
  const float* bc0 = (const float*)d_in[5];
  const float* Wid0 = (const float*)d_in[6];
  const float* bid0 = (const float*)d_in[7];
  const float* gm0 = (const float*)d_in[8];
  const float* bt0 = (const float*)d_in[9];
  const float* Wc1 = (const float*)d_in[10];
  const float* bc1 = (const float*)d_in[11];
  const float* Wid1 = (const float*)d_in[12];
  const float* bid1 = (const float*)d_in[13];
  const float* gm1 = (const float*)d_in[14];
  const float* bt1 = (const float*)d_in[15];
  const float* Wf1 = (const float*)d_in[16];
  const float* bf1 = (const float*)d_in[17];
  const float* Wf2 = (const float*)d_in[18];
  const float* bf2 = (const float*)d_in[19];
  const int* srcI = ei;
  const int* dstI = ei + NE;
  float* outp = (float*)d_out;

  char* ws = (char*)d_ws;
  size_t off = 0;
  auto take = [&](size_t bytes) -> char* {
    char* p = ws + off;
    off = (off + bytes + 255) & ~(size_t)255;
    return p;
  };
  float* dinv = (float*)take((size_t)NB * 4);
  int* cnt = (int*)take((size_t)NB * 4);
  int* starts = (int*)take((size_t)NB * 4);
  int* bsum = (int*)take((size_t)SCAN_NBLK * 4);
  int* esrc = (int*)take((size_t)NE * 4);
  float* stats1 = (float*)take((size_t)NREP * 2 * C1 * 4);
  float* stats2 = (float*)take((size_t)NREP * 2 * C2 * 4);
  float* sc1 = (float*)take(C1 * 4);
  float* sh1 = (float*)take(C1 * 4);
  float* sc2 = (float*)take(C2 * 4);
  float* sh2 = (float*)take(C2 * 4);
  float* counts = (float*)take((size_t)NG * 4);
  float* pooled = (float*)take((size_t)NG * C2 * 4);
  unsigned short* Wtf1 = (unsigned short*)take((size_t)4 * C0 * C1 * 2);
  unsigned short* Wtf2 = (unsigned short*)take((size_t)4 * C1 * C2 * 2);
  unsigned short* out1 = (unsigned short*)take((size_t)NN * C1 * 2);
  const size_t min_agg = (size_t)3 * 64 * C1 * 2;
  if (off + min_agg > ws_size) {
    k_fill<<<(out_size + 255) / 256, 256, 0, stream>>>(outp, out_size, 100.f);
    return;
  }
  unsigned short* aggXb = (unsigned short*)(ws + off);
  const size_t left = ws_size - off;
  long long ch1 = (long long)(left / ((size_t)3 * C0 * 2)) & ~63LL;
  long long ch2 = (long long)(left / ((size_t)3 * C1 * 2)) & ~63LL;
  if (ch1 > NN) ch1 = NN;
  if (ch2 > NN) ch2 = NN;

  dim3 blk(256);
  hipMemsetAsync(cnt, 0, (size_t)NB * 4, stream);
  hipMemsetAsync(stats1, 0, (size_t)NREP * 2 * C1 * 4, stream);
  hipMemsetAsync(stats2, 0, (size_t)NREP * 2 * C2 * 4, stream);
  hipMemsetAsync(counts, 0, (size_t)NG * 4, stream);
  hipMemsetAsync(pooled, 0, (size_t)NG * C2 * 4, stream);

  // ---- CSR build (histogram doubles as degree) ----
  k_hist<<<(NE + 255) / 256, blk, 0, stream>>>(dstI, et, cnt);
  k_dinvI<<<(NB + 255) / 256, blk, 0, stream>>>(cnt, dinv);
  k_counts<<<(NN + 255) / 256, blk, 0, stream>>>(batch, counts);
  k_scan1<<<SCAN_NBLK, blk, 0, stream>>>(cnt, starts, bsum);
  k_scan2<<<1, 64, 0, stream>>>(bsum);
  k_scan3<<<(NB + 255) / 256, blk, 0, stream>>>(starts, bsum);
  k_place<<<(NE + 255) / 256, blk, 0, stream>>>(srcI, dstI, et, starts, esrc);

  k_prepw<<<(4 * C0 * C1 + 255) / 256, blk, 0, stream>>>(Wid0, Wc0, Wtf1, C0, C1);
  k_prepw<<<(4 * C1 * C2 + 255) / 256, blk, 0, stream>>>(Wid1, Wc1, Wtf2, C1, C2);

  // ---- layer 1: x (f32, 32ch) -> out1 bf16 pre-BN (128ch) + stats1 ----
  for (long long lo = 0; lo < NN; lo += ch1) {
    const int nloc = (int)((NN - lo < ch1) ? (NN - lo) : ch1);
    const int nt = nloc / 64;
    const int nt2 = (nt + 1) >> 1;
    const int nt2_8 = (nt2 + 7) & ~7;
    k_agg<C0, float><<<(3 * nloc * 8 + 255) / 256, blk, 0, stream>>>(starts, esrc, dinv, x, aggXb,
                                                                     (int)lo, nloc);
    k_fin<C0, C1, false, true, false><<<nt2_8 * (C1 / 64), blk, 0, stream>>>(
        x, aggXb, (int)lo, nloc, nt, Wtf1, bid0, bc0, out1, stats1, nullptr, nullptr);
  }
  k_bnfin<<<1, blk, 0, stream>>>(stats1, gm0, bt0, sc1, sh1, C1);
  k_bnfold<<<(int)(((size_t)NN * C1 / 8 + 255) / 256), blk, 0, stream>>>(out1, sc1, sh1);

  // ---- layer 2: out1 bf16 (BN1 folded) -> stats2 + pre-BN pooled ----
  for (long long lo = 0; lo < NN; lo += ch2) {
    const int nloc = (int)((NN - lo < ch2) ? (NN - lo) : ch2);
    const int nt = nloc / 64;
    const int nt2 = (nt + 1) >> 1;
    const int nt2_8 = (nt2 + 7) & ~7;
    k_agg<C1, unsigned short><<<(3 * nloc * 16 + 255) / 256, blk, 0, stream>>>(starts, esrc, dinv, out1,
                                                                               aggXb, (int)lo, nloc);
    k_fin<C1, C2, true, false, true><<<nt2_8 * (C2 / 64), blk, 0, stream>>>(
        out1, aggXb, (int)lo, nloc, nt, Wtf2, bid1, bc1, nullptr, stats2, pooled, batch);
  }
  k_bnfin<<<1, blk, 0, stream>>>(stats2, gm1, bt1, sc2, sh2, C2);

  // ---- MLP head ----
  k_mlp<<<NG / MGB, blk, 0, stream>>>(pooled, counts, sc2, sh2, Wf1, bf1, Wf2, bf2, outp);
}

// Round 14
// 607.692 us; speedup vs baseline: 1.1345x; 1.1345x over previous
//
#include <hip/hip_runtime.h>
#include <cstdint>
#include <cstddef>

#define NN 200000
#define NE 600000
#define NG 8192
#define C0 32
#define C1 128
#define C2 256
#define MLPH 256
#define NCLS 10
#define NB (3 * NN)
#define SCAN_BPB 1024
#define SCAN_NBLK ((NB + SCAN_BPB - 1) / SCAN_BPB)
#define NREP 8   // stats atomic replication
#define MGB 32   // graphs per k_mlp block

typedef __attribute__((ext_vector_type(8))) short short8b;  // 8 bf16 = 4 VGPR
typedef __attribute__((ext_vector_type(4))) float f32x4;

__device__ __forceinline__ void atomAddF(float* p, float v) { unsafeAtomicAdd(p, v); }

__device__ __forceinline__ float b2f(unsigned short u) {
  union { unsigned u; float f; } v; v.u = ((unsigned)u) << 16; return v.f;
}
__device__ __forceinline__ unsigned short f2b(float f) {  // RNE
  union { float f; unsigned u; } v; v.f = f;
  return (unsigned short)((v.u + 0x7FFF + ((v.u >> 16) & 1)) >> 16);
}

// ---------------- small utility kernels ----------------
__global__ __launch_bounds__(256) void k_fill(float* __restrict__ p, int n, float v) {
  int i = blockIdx.x * 256 + threadIdx.x;
  if (i < n) p[i] = v;
}

__global__ __launch_bounds__(256) void k_counts(const int* __restrict__ batch, float* __restrict__ counts) {
  int n = blockIdx.x * 256 + threadIdx.x;
  if (n < NN) atomAddF(&counts[batch[n]], 1.f);
}

// ---------------- CSR build: histogram (= degree), scan, place ----------------
__global__ __launch_bounds__(256) void k_hist(const int* __restrict__ dst, const int* __restrict__ et,
                                              int* __restrict__ cnt) {
  int e = blockIdx.x * 256 + threadIdx.x;
  if (e < NE) atomicAdd(&cnt[et[e] * NN + dst[e]], 1);
}

__global__ __launch_bounds__(256) void k_dinvI(const int* __restrict__ cnt, float* __restrict__ dinv) {
  int i = blockIdx.x * 256 + threadIdx.x;
  if (i < NB) { int c = cnt[i]; dinv[i] = (c > 0) ? 1.f / sqrtf((float)c) : 0.f; }
}

__global__ __launch_bounds__(256) void k_scan1(const int* __restrict__ cnt, int* __restrict__ starts,
                                               int* __restrict__ bsum) {
  __shared__ int sh[256];
  const int b0 = blockIdx.x * SCAN_BPB + threadIdx.x * 4;
  int v[4]; int tot = 0;
#pragma unroll
  for (int j = 0; j < 4; j++) {
    int b = b0 + j;
    v[j] = tot;
    tot += (b < NB) ? cnt[b] : 0;
  }
  sh[threadIdx.x] = tot;
  __syncthreads();
  for (int ofs = 1; ofs < 256; ofs <<= 1) {
    int add = (threadIdx.x >= ofs) ? sh[threadIdx.x - ofs] : 0;
    __syncthreads();
    sh[threadIdx.x] += add;
    __syncthreads();
  }
  const int excl = (threadIdx.x == 0) ? 0 : sh[threadIdx.x - 1];
#pragma unroll
  for (int j = 0; j < 4; j++) {
    int b = b0 + j;
    if (b < NB) starts[b] = excl + v[j];
  }
  if (threadIdx.x == 255) bsum[blockIdx.x] = sh[255];
}

__global__ void k_scan2(int* __restrict__ bsum) {
  if (threadIdx.x == 0) {
    int acc = 0;
    for (int i = 0; i < SCAN_NBLK; i++) { int t = bsum[i]; bsum[i] = acc; acc += t; }
  }
}

__global__ __launch_bounds__(256) void k_scan3(int* __restrict__ starts, const int* __restrict__ bsum) {
  int b = blockIdx.x * 256 + threadIdx.x;
  if (b < NB) starts[b] += bsum[b / SCAN_BPB];
}

// After k_place, starts[b] == end(b); list for bin b = [b ? starts[b-1] : 0, starts[b])
__global__ __launch_bounds__(256) void k_place(const int* __restrict__ src, const int* __restrict__ dst,
                                               const int* __restrict__ et, int* __restrict__ starts,
                                               int* __restrict__ esrc) {
  int e = blockIdx.x * 256 + threadIdx.x;
  if (e >= NE) return;
  int b = et[e] * NN + dst[e];
  int pos = atomicAdd(&starts[b], 1);
  esrc[pos] = src[e];
}

// ---------------- weight prep: fragment-ordered bf16 ----------------
// [m:4][p:COUT/64][kk:CIN/32][ct:4][l:64][j:8]; ki = kk*32+(l>>4)*4+(j&3)+16*(j>>2), c = p*64+ct*16+(l&15)
__global__ __launch_bounds__(256) void k_prepw(const float* __restrict__ Wid, const float* __restrict__ Wc,
                                               unsigned short* __restrict__ Wtf, int CIN_, int COUT_) {
  int i = blockIdx.x * 256 + threadIdx.x;
  if (i >= 4 * CIN_ * COUT_) return;
  int j = i & 7, lq = (i >> 3) & 63, ct = (i >> 9) & 3;
  int rest = i >> 11;
  int KK = CIN_ / 32, NP = COUT_ / 64;
  int kk = rest % KK; rest /= KK;
  int p = rest % NP; int m = rest / NP;
  int ki = kk * 32 + (lq >> 4) * 4 + (j & 3) + 16 * (j >> 2);
  int c = p * 64 + ct * 16 + (lq & 15);
  float wv = (m == 0) ? Wid[(size_t)ki * COUT_ + c] : Wc[(size_t)((m - 1) * CIN_ + ki) * COUT_ + c];
  Wtf[i] = f2b(wv);
}

// ---------------- gather-reduce aggregation (CSR) ----------------
template <int CIN, typename TIN>
__global__ __launch_bounds__(256) void k_agg(const int* __restrict__ starts, const int* __restrict__ esrc,
                                             const float* __restrict__ dinv, const TIN* __restrict__ h,
                                             unsigned short* __restrict__ aggXb, int lo, int nloc) {
  constexpr int TPB = (CIN == 32) ? 8 : 16;
  constexpr int V = CIN / TPB;  // 4 (f32) or 8 (bf16)
  const int idx = blockIdx.x * 256 + threadIdx.x;
  const int bl = idx / TPB;
  const int lane = idx % TPB;
  if (bl >= 3 * nloc) return;
  const int t = bl / nloc;
  const int bin = t * NN + lo + (bl - t * nloc);
  const int s = (bin == 0) ? 0 : starts[bin - 1];
  const int e2 = starts[bin];
  float acc[V];
#pragma unroll
  for (int j = 0; j < V; j++) acc[j] = 0.f;
  for (int i = s; i < e2; i++) {
    const int sn = esrc[i];
    const float dv = dinv[(size_t)t * NN + sn];
    if (dv == 0.f) continue;
    const TIN* hp = h + (size_t)sn * CIN + lane * V;
    if constexpr (sizeof(TIN) == 2) {
      ushort4 u0 = *(const ushort4*)hp;
      ushort4 u1 = *(const ushort4*)((const unsigned short*)hp + 4);
      acc[0] = fmaf(b2f(u0.x), dv, acc[0]); acc[1] = fmaf(b2f(u0.y), dv, acc[1]);
      acc[2] = fmaf(b2f(u0.z), dv, acc[2]); acc[3] = fmaf(b2f(u0.w), dv, acc[3]);
      if constexpr (V == 8) {
        acc[4] = fmaf(b2f(u1.x), dv, acc[4]); acc[5] = fmaf(b2f(u1.y), dv, acc[5]);
        acc[6] = fmaf(b2f(u1.z), dv, acc[6]); acc[7] = fmaf(b2f(u1.w), dv, acc[7]);
      }
    } else {
      float4 v0 = *(const float4*)hp;
      acc[0] = fmaf(v0.x, dv, acc[0]); acc[1] = fmaf(v0.y, dv, acc[1]);
      acc[2] = fmaf(v0.z, dv, acc[2]); acc[3] = fmaf(v0.w, dv, acc[3]);
    }
  }
  const float dvd = dinv[bin];
  unsigned short* op = aggXb + (size_t)bl * CIN + lane * V;
  ushort4 o0;
  o0.x = f2b(acc[0] * dvd); o0.y = f2b(acc[1] * dvd);
  o0.z = f2b(acc[2] * dvd); o0.w = f2b(acc[3] * dvd);
  *(ushort4*)op = o0;
  if constexpr (V == 8) {
    ushort4 o1;
    o1.x = f2b(acc[4] * dvd); o1.y = f2b(acc[5] * dvd);
    o1.z = f2b(acc[6] * dvd); o1.w = f2b(acc[7] * dvd);
    *(ushort4*)(op + 4) = o1;
  }
}

// ---------------- fused finish via bf16 MFMA, LDS-staged weights, m-pipelined ----------------
// Round-12 structure (per-tile blocks, XCD-swizzled panels) + T14 split stage
// (SLOAD regs early / SWRITE LDS late) + A-fragments prefetched one m ahead.
#define SLOAD(mm)                                                                        \
  {                                                                                      \
    const short8b* g_ = (const short8b*)Wtf + (size_t)((mm) * NP + p) * PMF;             \
    _Pragma("unroll") for (int ii_ = 0; ii_ < KK; ii_++) wreg[ii_] = g_[ii_ * 256 + tid];\
  }

#define SWRITE(mm)                                                                       \
  {                                                                                      \
    short8b* d_ = wlds + ((mm) & 1) * PMF;                                               \
    _Pragma("unroll") for (int ii_ = 0; ii_ < KK; ii_++) d_[ii_ * 256 + tid] = wreg[ii_];\
  }

#define LOADA_M(A0, A1, mm)                                                              \
  {                                                                                      \
    if constexpr ((mm) > 0) {                                                            \
      const unsigned short* ar_ = aggXb + ((size_t)((mm)-1) * nloc + ln0 + rA) * CIN;    \
      _Pragma("unroll") for (int kk_ = 0; kk_ < KK; kk_++) {                             \
        A0[kk_] = *(const ushort4*)(ar_ + kk_ * 32 + lq * 4);                            \
        A1[kk_] = *(const ushort4*)(ar_ + kk_ * 32 + 16 + lq * 4);                       \
      }                                                                                  \
    } else if constexpr (INBF16) {                                                       \
      const unsigned short* xr_ = (const unsigned short*)Xv + (size_t)nA * CIN;          \
      _Pragma("unroll") for (int kk_ = 0; kk_ < KK; kk_++) {                             \
        A0[kk_] = *(const ushort4*)(xr_ + kk_ * 32 + lq * 4);                            \
        A1[kk_] = *(const ushort4*)(xr_ + kk_ * 32 + 16 + lq * 4);                       \
      }                                                                                  \
    } else {                                                                             \
      const float* xr_ = (const float*)Xv + (size_t)nA * CIN;                            \
      _Pragma("unroll") for (int kk_ = 0; kk_ < KK; kk_++) {                             \
        float4 v0_ = *(const float4*)(xr_ + kk_ * 32 + lq * 4);                          \
        float4 v1_ = *(const float4*)(xr_ + kk_ * 32 + 16 + lq * 4);                     \
        A0[kk_] = make_ushort4(f2b(v0_.x), f2b(v0_.y), f2b(v0_.z), f2b(v0_.w));          \
        A1[kk_] = make_ushort4(f2b(v1_.x), f2b(v1_.y), f2b(v1_.z), f2b(v1_.w));          \
      }                                                                                  \
    }                                                                                    \
  }

#define COMPM(A0, A1, mm)                                                                \
  {                                                                                      \
    f32x4 acc_[4];                                                                       \
    _Pragma("unroll") for (int c_ = 0; c_ < 4; c_++) acc_[c_] = (f32x4){0.f, 0.f, 0.f, 0.f}; \
    const short8b* wb_ = wlds + ((mm) & 1) * PMF;                                        \
    _Pragma("unroll") for (int kk_ = 0; kk_ < KK; kk_++) {                               \
      union { ushort4 u4[2]; short8b v; } fa_;                                           \
      fa_.u4[0] = A0[kk_]; fa_.u4[1] = A1[kk_];                                          \
      _Pragma("unroll") for (int c_ = 0; c_ < 4; c_++)                                   \
          acc_[c_] = __builtin_amdgcn_mfma_f32_16x16x32_bf16(                            \
              fa_.v, wb_[kk_ * 256 + c_ * 64 + l], acc_[c_], 0, 0, 0);                   \
    }                                                                                    \
    const float* bp_ = ((mm) == 0) ? bid : bc + (size_t)((mm)-1) * COUT;                 \
    _Pragma("unroll") for (int c_ = 0; c_ < 4; c_++) {                                   \
      float bb_ = bp_[c0 + c_ * 16 + lr];                                                \
      _Pragma("unroll") for (int j_ = 0; j_ < 4; j_++)                                   \
          run[c_][j_] += fmaxf(acc_[c_][j_] + bb_, 0.f);                                 \
    }                                                                                    \
  }

template <int CIN, int COUT, bool INBF16, bool WRITEOUT, bool DOPOOL>
__global__ __launch_bounds__(256, 3) void k_fin(
    const void* __restrict__ Xv, const unsigned short* __restrict__ aggXb,
    int lo, int nloc, int nt, const unsigned short* __restrict__ Wtf,
    const float* __restrict__ bid, const float* __restrict__ bc,
    unsigned short* __restrict__ outb, float* __restrict__ stats,
    float* __restrict__ pooled, const int* __restrict__ batch) {
  constexpr int NP = COUT / 64;
  constexpr int KK = CIN / 32;
  constexpr int PMF = KK * 256;                       // frags per (m,panel) slice
  constexpr int EPI = 64 * 65 * 4 + 2 * 4 * 64 * 4 + 64 * 4;  // tile + sred + sbatch
  constexpr int SMEM_BYTES = (2 * PMF * 16 > EPI) ? 2 * PMF * 16 : EPI;
  __shared__ __align__(16) char smem[SMEM_BYTES];
  short8b* wlds = (short8b*)smem;                     // [2][PMF]
  float (*tile)[65] = (float(*)[65])smem;             // epilogue aliases
  float* sred = (float*)(smem + 64 * 65 * 4);         // [2][4][64]
  int* sbatch = (int*)(smem + 64 * 65 * 4 + 2 * 4 * 64 * 4);

  // ---- XCD swizzle decode: i = xr8 + 8*(ti*NP + p) ----
  const int i = blockIdx.x;
  const int xr8 = i & 7;
  const int xq = i >> 3;
  const int p = xq % NP;
  const int ti = xq / NP;
  const int tileIdx = ti * 8 + xr8;
  if (tileIdx >= nt) return;
  const int ln0 = tileIdx * 64;
  const int n0 = lo + ln0;
  const int c0 = p * 64;
  const int tid = threadIdx.x, w = tid >> 6, l = tid & 63, lr = l & 15, lq = l >> 4;
  const int rA = w * 16 + lr;
  const int nA = n0 + rA;

  f32x4 run[4];
#pragma unroll
  for (int ct = 0; ct < 4; ct++) run[ct] = (f32x4){0.f, 0.f, 0.f, 0.f};

  short8b wreg[KK];
  ushort4 a0A[KK], a1A[KK], a0B[KK], a1B[KK];

  // ---- prologue: stage m0 weights + load A(0); both in flight together ----
  SLOAD(0)
  LOADA_M(a0A, a1A, 0)
  SWRITE(0)
  __syncthreads();
  // ---- m=0 ----
  SLOAD(1)
  LOADA_M(a0B, a1B, 1)
  COMPM(a0A, a1A, 0)
  SWRITE(1)
  __syncthreads();
  // ---- m=1 ----
  SLOAD(2)
  LOADA_M(a0A, a1A, 2)
  COMPM(a0B, a1B, 1)
  SWRITE(2)
  __syncthreads();
  // ---- m=2 ----
  SLOAD(3)
  LOADA_M(a0B, a1B, 3)
  COMPM(a0A, a1A, 2)
  SWRITE(3)
  __syncthreads();
  // ---- m=3 ----
  COMPM(a0B, a1B, 3)
  __syncthreads();  // all waves done reading wlds before epilogue aliases it

  // ---- epilogue (smem aliased as tile/sred/sbatch) ----
#pragma unroll
  for (int ct = 0; ct < 4; ct++)
#pragma unroll
    for (int j = 0; j < 4; j++) tile[w * 16 + lq * 4 + j][ct * 16 + lr] = run[ct][j];
  if (DOPOOL && tid < 64) sbatch[tid] = batch[n0 + tid];
  __syncthreads();

  if (WRITEOUT) {
    const int r = tid >> 2, cg = (tid & 3) * 16;
    ushort4 o[4];
#pragma unroll
    for (int g4 = 0; g4 < 4; g4++) {
      o[g4].x = f2b(tile[r][cg + g4 * 4 + 0]);
      o[g4].y = f2b(tile[r][cg + g4 * 4 + 1]);
      o[g4].z = f2b(tile[r][cg + g4 * 4 + 2]);
      o[g4].w = f2b(tile[r][cg + g4 * 4 + 3]);
    }
    ushort4* dst4 = (ushort4*)(outb + (size_t)(n0 + r) * COUT + c0 + cg);
#pragma unroll
    for (int g4 = 0; g4 < 4; g4++) dst4[g4] = o[g4];
  }
  {  // parallel stats + pool: thread = (rowgroup rg, col)
    const int col = tid & 63, rg = tid >> 6, r0 = rg * 16;
    float s = 0.f, ss = 0.f, gs = 0.f;
    int curg = DOPOOL ? sbatch[r0] : 0;
#pragma unroll
    for (int r = 0; r < 16; r++) {
      float v = tile[r0 + r][col];
      s += v; ss += v * v;
      if (DOPOOL) {
        int g = sbatch[r0 + r];
        if (g != curg) { atomAddF(&pooled[(size_t)curg * C2 + c0 + col], gs); gs = 0.f; curg = g; }
        gs += v;
      }
    }
    if (DOPOOL) atomAddF(&pooled[(size_t)curg * C2 + c0 + col], gs);
    sred[0 * 4 * 64 + rg * 64 + col] = s;
    sred[1 * 4 * 64 + rg * 64 + col] = ss;
  }
  __syncthreads();
  if (tid < 64) {
    float s4 = sred[0 + tid] + sred[64 + tid] + sred[128 + tid] + sred[192 + tid];
    float ss4 = sred[256 + tid] + sred[320 + tid] + sred[384 + tid] + sred[448 + tid];
    float* st = stats + (size_t)(tileIdx & (NREP - 1)) * 2 * COUT;
    atomAddF(&st[c0 + tid], s4);
    atomAddF(&st[COUT + c0 + tid], ss4);
  }
}

// ---------------- BN finalize (sums NREP replicas) -> per-channel scale/shift ----------------
__global__ __launch_bounds__(256) void k_bnfin(const float* __restrict__ stats, const float* __restrict__ gamma,
                                               const float* __restrict__ beta, float* __restrict__ sc,
                                               float* __restrict__ sh, int COUT) {
  int c = threadIdx.x;
  if (c < COUT) {
    float su = 0.f, ssu = 0.f;
    for (int r = 0; r < NREP; r++) {
      su += stats[(size_t)r * 2 * COUT + c];
      ssu += stats[(size_t)r * 2 * COUT + COUT + c];
    }
    const float invN = 1.f / (float)NN;
    float m = su * invN;
    float v = ssu * invN - m * m;
    float s = gamma[c] / sqrtf(v + 1e-5f);
    sc[c] = s;
    sh[c] = fmaf(-m, s, beta[c]);
  }
}

// ---------------- fold BN1 into out1 (bf16, in place) ----------------
__global__ __launch_bounds__(256) void k_bnfold(unsigned short* __restrict__ o, const float* __restrict__ sc,
                                                const float* __restrict__ sh) {
  size_t i8 = ((size_t)blockIdx.x * 256 + threadIdx.x) * 8;
  if (i8 >= (size_t)NN * C1) return;
  const int c = (int)(i8 & (C1 - 1));
  ushort4 a = *(ushort4*)(o + i8);
  ushort4 b = *(ushort4*)(o + i8 + 4);
  a.x = f2b(fmaf(b2f(a.x), sc[c + 0], sh[c + 0]));
  a.y = f2b(fmaf(b2f(a.y), sc[c + 1], sh[c + 1]));
  a.z = f2b(fmaf(b2f(a.z), sc[c + 2], sh[c + 2]));
  a.w = f2b(fmaf(b2f(a.w), sc[c + 3], sh[c + 3]));
  b.x = f2b(fmaf(b2f(b.x), sc[c + 4], sh[c + 4]));
  b.y = f2b(fmaf(b2f(b.y), sc[c + 5], sh[c + 5]));
  b.z = f2b(fmaf(b2f(b.z), sc[c + 6], sh[c + 6]));
  b.w = f2b(fmaf(b2f(b.w), sc[c + 7], sh[c + 7]));
  *(ushort4*)(o + i8) = a;
  *(ushort4*)(o + i8 + 4) = b;
}

// ---------------- MLP head, graph-tiled: 32 graphs/block, Wf1 read once per block ----------------
__global__ __launch_bounds__(256) void k_mlp(const float* __restrict__ pooled, const float* __restrict__ counts,
                                             const float* __restrict__ sc2, const float* __restrict__ sh2,
                                             const float* __restrict__ Wf1, const float* __restrict__ bf1,
                                             const float* __restrict__ Wf2, const float* __restrict__ bf2,
                                             float* __restrict__ out) {
  __shared__ float featT[257 * 36];  // [i][g], pad 36 (16B-aligned rows); aliased as hidT[256][36]
  __shared__ float cnts[MGB];
  const int g0 = blockIdx.x * MGB;
  const int t = threadIdx.x;
  if (t < MGB) cnts[t] = counts[g0 + t];
  __syncthreads();
  {
    const float sc = sc2[t], sh = sh2[t];
    for (int g = 0; g < MGB; g++)
      featT[t * 36 + g] = fmaf(sc, pooled[(size_t)(g0 + g) * C2 + t], sh * cnts[g]);
  }
  if (t < MGB) featT[256 * 36 + t] = cnts[t] * 0.025f;  // count/40 feature
  __syncthreads();
  float acc[MGB];
  const float b1 = bf1[t];
#pragma unroll
  for (int g = 0; g < MGB; g++) acc[g] = b1;
  for (int i = 0; i < 257; i++) {
    const float wv = Wf1[(size_t)i * MLPH + t];
    const float* fr = &featT[i * 36];
#pragma unroll
    for (int g4 = 0; g4 < MGB / 4; g4++) {
      float4 fg = *(const float4*)(fr + g4 * 4);
      acc[g4 * 4 + 0] = fmaf(fg.x, wv, acc[g4 * 4 + 0]);
      acc[g4 * 4 + 1] = fmaf(fg.y, wv, acc[g4 * 4 + 1]);
      acc[g4 * 4 + 2] = fmaf(fg.z, wv, acc[g4 * 4 + 2]);
      acc[g4 * 4 + 3] = fmaf(fg.w, wv, acc[g4 * 4 + 3]);
    }
  }
  __syncthreads();  // featT fully consumed
  float* hidT = featT;  // alias: [j][g] with stride 36
#pragma unroll
  for (int g = 0; g < MGB; g++) hidT[t * 36 + g] = fmaxf(acc[g], 0.f);
  __syncthreads();
  for (int task = t; task < MGB * NCLS; task += 256) {
    const int g = task / NCLS, c = task % NCLS;
    float o = bf2[c];
    for (int j = 0; j < MLPH; j++) o = fmaf(hidT[j * 36 + g], Wf2[(size_t)j * NCLS + c], o);
    out[(size_t)(g0 + g) * NCLS + c] = o;
  }
}

extern "C" void kernel_launch(void* const* d_in, const int* in_sizes, int n_in,
                              void* d_out, int out_size, void* d_ws, size_t ws_size,
                              hipStream_t stream) {
  const float* x = (const float*)d_in[0];
  const int* ei = (const int*)d_in[1];
  const int* et = (const int*)d_in[2];
  const int* batch = (const int*)d_in[3];
  const float* Wc0 = (const float*)d_in[4];
  const float* bc0 = (const float*)d_in[5];
  const float* Wid0 = (const float*)d_in[6];
  const float* bid0 = (const float*)d_in[7];
  const float* gm0 = (const float*)d_in[8];
  const float* bt0 = (const float*)d_in[9];
  const float* Wc1 = (const float*)d_in[10];
  const float* bc1 = (const float*)d_in[11];
  const float* Wid1 = (const float*)d_in[12];
  const float* bid1 = (const float*)d_in[13];
  const float* gm1 = (const float*)d_in[14];
  const float* bt1 = (const float*)d_in[15];
  const float* Wf1 = (const float*)d_in[16];
  const float* bf1 = (const float*)d_in[17];
  const float* Wf2 = (const float*)d_in[18];
  const float* bf2 = (const float*)d_in[19];
  const int* srcI = ei;
  const int* dstI = ei + NE;
  float* outp = (float*)d_out;

  char* ws = (char*)d_ws;
  size_t off = 0;
  auto take = [&](size_t bytes) -> char* {
    char* p = ws + off;
    off = (off + bytes + 255) & ~(size_t)255;
    return p;
  };
  float* dinv = (float*)take((size_t)NB * 4);
  int* cnt = (int*)take((size_t)NB * 4);
  int* starts = (int*)take((size_t)NB * 4);
  int* bsum = (int*)take((size_t)SCAN_NBLK * 4);
  int* esrc = (int*)take((size_t)NE * 4);
  float* stats1 = (float*)take((size_t)NREP * 2 * C1 * 4);
  float* stats2 = (float*)take((size_t)NREP * 2 * C2 * 4);
  float* sc1 = (float*)take(C1 * 4);
  float* sh1 = (float*)take(C1 * 4);
  float* sc2 = (float*)take(C2 * 4);
  float* sh2 = (float*)take(C2 * 4);
  float* counts = (float*)take((size_t)NG * 4);
  float* pooled = (float*)take((size_t)NG * C2 * 4);
  unsigned short* Wtf1 = (unsigned short*)take((size_t)4 * C0 * C1 * 2);
  unsigned short* Wtf2 = (unsigned short*)take((size_t)4 * C1 * C2 * 2);
  unsigned short* out1 = (unsigned short*)take((size_t)NN * C1 * 2);
  const size_t min_agg = (size_t)3 * 64 * C1 * 2;
  if (off + min_agg > ws_size) {
    k_fill<<<(out_size + 255) / 256, 256, 0, stream>>>(outp, out_size, 100.f);
    return;
  }
  unsigned short* aggXb = (unsigned short*)(ws + off);
  const size_t left = ws_size - off;
  long long ch1 = (long long)(left / ((size_t)3 * C0 * 2)) & ~63LL;
  long long ch2 = (long long)(left / ((size_t)3 * C1 * 2)) & ~63LL;
  if (ch1 > NN) ch1 = NN;
  if (ch2 > NN) ch2 = NN;

  dim3 blk(256);
  hipMemsetAsync(cnt, 0, (size_t)NB * 4, stream);
  hipMemsetAsync(stats1, 0, (size_t)NREP * 2 * C1 * 4, stream);
  hipMemsetAsync(stats2, 0, (size_t)NREP * 2 * C2 * 4, stream);
  hipMemsetAsync(counts, 0, (size_t)NG * 4, stream);
  hipMemsetAsync(pooled, 0, (size_t)NG * C2 * 4, stream);

  // ---- CSR build (histogram doubles as degree) ----
  k_hist<<<(NE + 255) / 256, blk, 0, stream>>>(dstI, et, cnt);
  k_dinvI<<<(NB + 255) / 256, blk, 0, stream>>>(cnt, dinv);
  k_counts<<<(NN + 255) / 256, blk, 0, stream>>>(batch, counts);
  k_scan1<<<SCAN_NBLK, blk, 0, stream>>>(cnt, starts, bsum);
  k_scan2<<<1, 64, 0, stream>>>(bsum);
  k_scan3<<<(NB + 255) / 256, blk, 0, stream>>>(starts, bsum);
  k_place<<<(NE + 255) / 256, blk, 0, stream>>>(srcI, dstI, et, starts, esrc);

  k_prepw<<<(4 * C0 * C1 + 255) / 256, blk, 0, stream>>>(Wid0, Wc0, Wtf1, C0, C1);
  k_prepw<<<(4 * C1 * C2 + 255) / 256, blk, 0, stream>>>(Wid1, Wc1, Wtf2, C1, C2);

  // ---- layer 1: x (f32, 32ch) -> out1 bf16 pre-BN (128ch) + stats1 ----
  for (long long lo = 0; lo < NN; lo += ch1) {
    const int nloc = (int)((NN - lo < ch1) ? (NN - lo) : ch1);
    const int nt = nloc / 64;
    const int nt8 = (nt + 7) & ~7;
    k_agg<C0, float><<<(3 * nloc * 8 + 255) / 256, blk, 0, stream>>>(starts, esrc, dinv, x, aggXb,
                                                                     (int)lo, nloc);
    k_fin<C0, C1, false, true, false><<<nt8 * (C1 / 64), blk, 0, stream>>>(
        x, aggXb, (int)lo, nloc, nt, Wtf1, bid0, bc0, out1, stats1, nullptr, nullptr);
  }
  k_bnfin<<<1, blk, 0, stream>>>(stats1, gm0, bt0, sc1, sh1, C1);
  k_bnfold<<<(int)(((size_t)NN * C1 / 8 + 255) / 256), blk, 0, stream>>>(out1, sc1, sh1);

  // ---- layer 2: out1 bf16 (BN1 folded) -> stats2 + pre-BN pooled ----
  for (long long lo = 0; lo < NN; lo += ch2) {
    const int nloc = (int)((NN - lo < ch2) ? (NN - lo) : ch2);
    const int nt = nloc / 64;
    const int nt8 = (nt + 7) & ~7;
    k_agg<C1, unsigned short><<<(3 * nloc * 16 + 255) / 256, blk, 0, stream>>>(starts, esrc, dinv, out1,
                                                                               aggXb, (int)lo, nloc);
    k_fin<C1, C2, true, false, true><<<nt8 * (C2 / 64), blk, 0, stream>>>(
        out1, aggXb, (int)lo, nloc, nt, Wtf2, bid1, bc1, nullptr, stats2, pooled, batch);
  }
  k_bnfin<<<1, blk, 0, stream>>>(stats2, gm1, bt1, sc2, sh2, C2);

  // ---- MLP head ----
  k_mlp<<<NG / MGB, blk, 0, stream>>>(pooled, counts, sc2, sh2, Wf1, bf1, Wf2, bf2, outp);
}